// Round 9
// baseline (4875.190 us; speedup 1.0000x reference)
//
#include <hip/hip_runtime.h>

// ============================ 64-wide GEMM (encoders, tiny) ==================
#define BM 64
#define BN 64
#define BK 16

__global__ __launch_bounds__(256) void gemm_bias_kernel(
    const float* __restrict__ A, int lda,
    const float* __restrict__ W,        // [K, DOUT] row-major
    const float* __restrict__ bias,     // [DOUT]
    float* __restrict__ C, int ldc, int col0,
    int N, int K, int DOUT)
{
    __shared__ float As[BK][BM + 4];
    __shared__ float Bs[BK][BN + 4];
    const int tid = threadIdx.x;
    const int tx = tid & 15, ty = tid >> 4;
    const int m0 = blockIdx.x * BM, n0 = blockIdx.y * BN;
    float acc[4][4] = {};
    const int ar = tid >> 2, ak = (tid & 3) << 2;
    const int br = tid >> 4, bn = (tid & 15) << 2;

    for (int k0 = 0; k0 < K; k0 += BK) {
        float4 av = make_float4(0.f, 0.f, 0.f, 0.f);
        int grow = m0 + ar, gk = k0 + ak;
        if (grow < N) {
            if (gk + 3 < K) {
                av = *(const float4*)(A + (long long)grow * lda + gk);
            } else {
                float t0 = 0.f, t1 = 0.f, t2 = 0.f, t3 = 0.f;
                if (gk + 0 < K) t0 = A[(long long)grow * lda + gk + 0];
                if (gk + 1 < K) t1 = A[(long long)grow * lda + gk + 1];
                if (gk + 2 < K) t2 = A[(long long)grow * lda + gk + 2];
                if (gk + 3 < K) t3 = A[(long long)grow * lda + gk + 3];
                av = make_float4(t0, t1, t2, t3);
            }
        }
        As[ak + 0][ar] = av.x; As[ak + 1][ar] = av.y;
        As[ak + 2][ar] = av.z; As[ak + 3][ar] = av.w;

        float4 bv = make_float4(0.f, 0.f, 0.f, 0.f);
        int gbk = k0 + br, gn = n0 + bn;
        if (gbk < K && gn + 3 < DOUT)
            bv = *(const float4*)(W + (long long)gbk * DOUT + gn);
        *(float4*)&Bs[br][bn] = bv;
        __syncthreads();

        #pragma unroll
        for (int kk = 0; kk < BK; ++kk) {
            float4 a4 = *(const float4*)&As[kk][ty << 2];
            float4 b4 = *(const float4*)&Bs[kk][tx << 2];
            float a[4] = {a4.x, a4.y, a4.z, a4.w};
            float b[4] = {b4.x, b4.y, b4.z, b4.w};
            #pragma unroll
            for (int i = 0; i < 4; ++i)
                #pragma unroll
                for (int j = 0; j < 4; ++j)
                    acc[i][j] = fmaf(a[i], b[j], acc[i][j]);
        }
        __syncthreads();
    }

    #pragma unroll
    for (int i = 0; i < 4; ++i) {
        int gm = m0 + (ty << 2) + i;
        if (gm >= N) continue;
        #pragma unroll
        for (int j = 0; j < 4; ++j) {
            int gn = n0 + (tx << 2) + j;
            if (gn < DOUT)
                C[(long long)gm * ldc + col0 + gn] = acc[i][j] + bias[gn];
        }
    }
}

// ============== 128x128 GEMM, double-buffered LDS (layer transforms) =========
// requires: K % 16 == 0, DOUT % 128 == 0
#define GM 128
#define GN 128
#define GK 16

__global__ __launch_bounds__(256) void gemm128_kernel(
    const float* __restrict__ A, int lda,
    const float* __restrict__ W,
    const float* __restrict__ bias,
    float* __restrict__ C, int ldc, int col0,
    int N, int K, int DOUT)
{
    __shared__ float As[2][GK][GM + 4];
    __shared__ float Bs[2][GK][GN + 4];
    const int tid = threadIdx.x;
    const int tx = tid & 15, ty = tid >> 4;
    const int m0 = blockIdx.x * GM, n0 = blockIdx.y * GN;
    float acc[8][8] = {};

    const int ar = tid >> 1, ak = (tid & 1) << 3;   // 128 rows x (2 x 8k)
    const int br = tid >> 4, bn = (tid & 15) << 3;  // 16 k x (16 x 8 cols)
    const long long arow = (long long)(m0 + ar) * lda;
    const bool aval = (m0 + ar) < N;

    float4 pa0 = make_float4(0.f,0.f,0.f,0.f), pa1 = pa0, pb0, pb1;
    if (aval) {
        pa0 = *(const float4*)(A + arow + ak);
        pa1 = *(const float4*)(A + arow + ak + 4);
    }
    pb0 = *(const float4*)(W + (long long)br * DOUT + n0 + bn);
    pb1 = *(const float4*)(W + (long long)br * DOUT + n0 + bn + 4);

    As[0][ak + 0][ar] = pa0.x; As[0][ak + 1][ar] = pa0.y;
    As[0][ak + 2][ar] = pa0.z; As[0][ak + 3][ar] = pa0.w;
    As[0][ak + 4][ar] = pa1.x; As[0][ak + 5][ar] = pa1.y;
    As[0][ak + 6][ar] = pa1.z; As[0][ak + 7][ar] = pa1.w;
    *(float4*)&Bs[0][br][bn]     = pb0;
    *(float4*)&Bs[0][br][bn + 4] = pb1;

    const int nt = K / GK;
    int cur = 0;
    for (int t = 0; t < nt; ++t) {
        __syncthreads();
        if (t + 1 < nt) {
            const int gk = (t + 1) * GK;
            pa0 = make_float4(0.f,0.f,0.f,0.f); pa1 = pa0;
            if (aval) {
                pa0 = *(const float4*)(A + arow + gk + ak);
                pa1 = *(const float4*)(A + arow + gk + ak + 4);
            }
            pb0 = *(const float4*)(W + (long long)(gk + br) * DOUT + n0 + bn);
            pb1 = *(const float4*)(W + (long long)(gk + br) * DOUT + n0 + bn + 4);
        }
        #pragma unroll
        for (int kk = 0; kk < GK; ++kk) {
            float4 aa0 = *(const float4*)&As[cur][kk][ty << 2];
            float4 aa1 = *(const float4*)&As[cur][kk][64 + (ty << 2)];
            float4 bb0 = *(const float4*)&Bs[cur][kk][tx << 2];
            float4 bb1 = *(const float4*)&Bs[cur][kk][64 + (tx << 2)];
            float a[8] = {aa0.x, aa0.y, aa0.z, aa0.w, aa1.x, aa1.y, aa1.z, aa1.w};
            float b[8] = {bb0.x, bb0.y, bb0.z, bb0.w, bb1.x, bb1.y, bb1.z, bb1.w};
            #pragma unroll
            for (int i = 0; i < 8; ++i)
                #pragma unroll
                for (int j = 0; j < 8; ++j)
                    acc[i][j] = fmaf(a[i], b[j], acc[i][j]);
        }
        if (t + 1 < nt) {
            const int nb = cur ^ 1;
            As[nb][ak + 0][ar] = pa0.x; As[nb][ak + 1][ar] = pa0.y;
            As[nb][ak + 2][ar] = pa0.z; As[nb][ak + 3][ar] = pa0.w;
            As[nb][ak + 4][ar] = pa1.x; As[nb][ak + 5][ar] = pa1.y;
            As[nb][ak + 6][ar] = pa1.z; As[nb][ak + 7][ar] = pa1.w;
            *(float4*)&Bs[nb][br][bn]     = pb0;
            *(float4*)&Bs[nb][br][bn + 4] = pb1;
        }
        cur ^= 1;
    }

    #pragma unroll
    for (int half = 0; half < 2; ++half) {
        #pragma unroll
        for (int i = 0; i < 4; ++i) {
            int gm = m0 + half * 64 + (ty << 2) + i;
            if (gm >= N) continue;
            int ai = half * 4 + i;
            #pragma unroll
            for (int jh = 0; jh < 2; ++jh) {
                int gn = n0 + jh * 64 + (tx << 2);
                float4 r;
                r.x = acc[ai][jh * 4 + 0] + bias[gn + 0];
                r.y = acc[ai][jh * 4 + 1] + bias[gn + 1];
                r.z = acc[ai][jh * 4 + 2] + bias[gn + 2];
                r.w = acc[ai][jh * 4 + 3] + bias[gn + 3];
                *(float4*)(C + (long long)gm * ldc + col0 + gn) = r;
            }
        }
    }
}

// ================= weight pack: Bp[k][et*dout+c] = W[etl[et]][k][c] ==========
__global__ void pack_w_kernel(const float* __restrict__ Wstack,
                              const float* __restrict__ bstack,
                              int din, int dout, int4 etl,
                              float* __restrict__ Bp, float* __restrict__ bp)
{
    const int idx = blockIdx.x * blockDim.x + threadIdx.x;
    const int wtot = din * 4 * dout;
    if (idx < wtot) {
        const int col = idx % (4 * dout), k = idx / (4 * dout);
        const int et = col / dout, c = col % dout;
        const int e = (&etl.x)[et];
        Bp[idx] = Wstack[((size_t)e * din + k) * dout + c];
    }
    if (idx < 4 * dout) {
        const int et = idx / dout, c = idx % dout;
        const int e = (&etl.x)[et];
        bp[idx] = bstack[e * dout + c];
    }
}

// ====================== CSR-gather aggregation kernels =======================
// out[node] (=|+=) (1/deg) * sum_{e in CSR[node]} Wh[csr[e]][colWh..]
template<int DOUT, bool ACC>
__global__ __launch_bounds__(256) void agg_wave_kernel(
    const float* __restrict__ Wh, int ldWh, int colWh,
    const int* __restrict__ roff, const int* __restrict__ csr,
    float* __restrict__ out, int ldo, int col0, int N)
{
    constexpr int CT = DOUT / 4;
    constexpr int NPB = 256 / CT;
    const int node = blockIdx.x * NPB + threadIdx.x / CT;
    if (node >= N) return;
    const int c = threadIdx.x % CT;
    const int beg = roff[node], end = roff[node + 1];
    float sx = 0.f, sy = 0.f, sz = 0.f, sw = 0.f;
    for (int e = beg; e < end; ++e) {
        const int s = csr[e];
        const float4 v = *(const float4*)(Wh + (long long)s * ldWh + colWh + (c << 2));
        sx += v.x; sy += v.y; sz += v.z; sw += v.w;
    }
    const int deg = end - beg;
    const float sc = deg > 0 ? 1.0f / (float)deg : 0.0f;
    float* po = out + (long long)node * ldo + col0 + (c << 2);
    float4 r; r.x = sx * sc; r.y = sy * sc; r.z = sz * sc; r.w = sw * sc;
    if (ACC) {
        const float4 o = *(const float4*)po;
        r.x += o.x; r.y += o.y; r.z += o.z; r.w += o.w;
    }
    *(float4*)po = r;
}

// ---- multi-block partial aggregation for tiny-N / huge-degree dsts (pt/ft) --
template<int DOUT>
__global__ __launch_bounds__(256) void agg_part_kernel(
    const float* __restrict__ Wh, int ldWh, int colWh,
    const int* __restrict__ roff, const int* __restrict__ csr,
    float* __restrict__ P, int SEGS)
{
    constexpr int CT = DOUT / 4;
    constexpr int EP = 256 / CT;
    const int node = blockIdx.x / SEGS;
    const int seg  = blockIdx.x % SEGS;
    const int c = threadIdx.x % CT;
    const int g = threadIdx.x / CT;
    const int beg = roff[node], end = roff[node + 1];
    float sx = 0.f, sy = 0.f, sz = 0.f, sw = 0.f;
    for (int e = beg + seg * EP + g; e < end; e += SEGS * EP) {
        const int s = csr[e];
        const float4 v = *(const float4*)(Wh + (long long)s * ldWh + colWh + (c << 2));
        sx += v.x; sy += v.y; sz += v.z; sw += v.w;
    }
    __shared__ float4 red[256];
    red[threadIdx.x] = make_float4(sx, sy, sz, sw);
    __syncthreads();
    if (g == 0) {
        #pragma unroll
        for (int k = 1; k < EP; ++k) {
            const float4 v = red[k * CT + c];
            sx += v.x; sy += v.y; sz += v.z; sw += v.w;
        }
        float* pp = P + (long long)node * DOUT + (c << 2);
        atomicAdd(pp + 0, sx);
        atomicAdd(pp + 1, sy);
        atomicAdd(pp + 2, sz);
        atomicAdd(pp + 3, sw);
    }
}

__global__ void agg_fin_kernel(const float* __restrict__ P,
                               const int* __restrict__ roff,
                               float* __restrict__ out, int ldo, int col0,
                               int N, int DOUT)
{
    int idx = blockIdx.x * blockDim.x + threadIdx.x;
    if (idx >= N * DOUT) return;
    int n = idx / DOUT, c = idx % DOUT;
    int deg = roff[n + 1] - roff[n];
    float sc = deg > 0 ? 1.0f / (float)deg : 0.0f;
    out[(long long)n * ldo + col0 + c] = P[idx] * sc;
}

__global__ void zero_f32_kernel(float* __restrict__ p, int n)
{
    int i = blockIdx.x * blockDim.x + threadIdx.x;
    if (i < n) p[i] = 0.f;
}

// ============================ CSR build helpers ==============================
__global__ void zero_i32_kernel(int* __restrict__ p, int n)
{
    int i = blockIdx.x * blockDim.x + threadIdx.x;
    if (i < n) p[i] = 0;
}

__global__ void count_kernel(const int* __restrict__ dst, int E, int* __restrict__ cnt)
{
    int i = blockIdx.x * blockDim.x + threadIdx.x;
    if (i < E) atomicAdd(&cnt[dst[i]], 1);
}

// 3-phase global exclusive scan over cnt[0..n) -> G[0..n], G[n]=tote
#define SCB 256
#define SCI 4
__global__ __launch_bounds__(SCB) void scan_p1_kernel(
    const int* __restrict__ cnt, int n, int* __restrict__ G, int* __restrict__ bsum)
{
    __shared__ int sh[SCB];
    const int base = blockIdx.x * (SCB * SCI);
    const int tb = base + threadIdx.x * SCI;
    int v[SCI]; int tsum = 0;
    #pragma unroll
    for (int j = 0; j < SCI; ++j) {
        int idx = tb + j;
        v[j] = (idx < n) ? cnt[idx] : 0;
        tsum += v[j];
    }
    sh[threadIdx.x] = tsum;
    __syncthreads();
    int incl = tsum;
    for (int ofs = 1; ofs < SCB; ofs <<= 1) {
        int t = (threadIdx.x >= (unsigned)ofs) ? sh[threadIdx.x - ofs] : 0;
        __syncthreads();
        incl += t;
        sh[threadIdx.x] = incl;
        __syncthreads();
    }
    if (threadIdx.x == SCB - 1) bsum[blockIdx.x] = incl;
    int run = incl - tsum;                 // exclusive prefix of this thread
    #pragma unroll
    for (int j = 0; j < SCI; ++j) {
        int idx = tb + j;
        if (idx < n) G[idx] = run;
        run += v[j];
    }
}

__global__ void scan_p2_kernel(int* __restrict__ bsum, int nb)
{
    if (blockIdx.x == 0 && threadIdx.x == 0) {
        int run = 0;
        for (int b = 0; b < nb; ++b) { int t = bsum[b]; bsum[b] = run; run += t; }
    }
}

__global__ void scan_p3_kernel(int* __restrict__ G, int n,
                               const int* __restrict__ bsum, int tote)
{
    int i = blockIdx.x * blockDim.x + threadIdx.x;
    if (i < n) G[i] += bsum[i / (SCB * SCI)];
    if (i == 0) G[n] = tote;
}

__global__ void fill_kernel(const int* __restrict__ src, const int* __restrict__ dst,
                            int E, const int* __restrict__ G,   // per-etype base
                            int* __restrict__ cur,              // per-etype base
                            int* __restrict__ csr)              // GLOBAL base
{
    int i = blockIdx.x * blockDim.x + threadIdx.x;
    if (i < E) {
        const int d = dst[i];
        const int pos = atomicAdd(&cur[d], 1);
        csr[G[d] + pos] = src[i];
    }
}

// ============================== misc kernels =================================
__global__ void bcast_kernel(const float* __restrict__ emb, float* __restrict__ Fp,
                             int ld, int N)
{
    int idx = blockIdx.x * blockDim.x + threadIdx.x;
    if (idx >= N * 128) return;
    int r = idx >> 7, c = idx & 127;
    Fp[(long long)r * ld + c] = emb[c];
}

__global__ void decoder_kernel(const float* __restrict__ H, int ld, int N,
                               const float* __restrict__ Wd,
                               const float* __restrict__ bd,
                               float* __restrict__ logits, float* __restrict__ soft)
{
    int n = blockIdx.x * blockDim.x + threadIdx.x;
    if (n >= N) return;
    const float* h = H + (long long)n * ld;
    float s0 = bd[0], s1 = bd[1];
    #pragma unroll
    for (int k = 0; k < 128; k += 4) {
        float4 hv = *(const float4*)(h + k);
        s0 = fmaf(hv.x, Wd[2 * (k + 0) + 0], s0); s1 = fmaf(hv.x, Wd[2 * (k + 0) + 1], s1);
        s0 = fmaf(hv.y, Wd[2 * (k + 1) + 0], s0); s1 = fmaf(hv.y, Wd[2 * (k + 1) + 1], s1);
        s0 = fmaf(hv.z, Wd[2 * (k + 2) + 0], s0); s1 = fmaf(hv.z, Wd[2 * (k + 2) + 1], s1);
        s0 = fmaf(hv.w, Wd[2 * (k + 3) + 0], s0); s1 = fmaf(hv.w, Wd[2 * (k + 3) + 1], s1);
    }
    logits[2 * n + 0] = s0;
    logits[2 * n + 1] = s1;
    float m = fmaxf(s0, s1);
    float e0 = expf(s0 - m), e1 = expf(s1 - m);
    float invs = 1.f / (e0 + e1);
    soft[2 * n + 0] = e0 * invs;
    soft[2 * n + 1] = e1 * invs;
}

// ================================== host =====================================
extern "C" void kernel_launch(void* const* d_in, const int* in_sizes, int n_in,
                              void* d_out, int out_size, void* d_ws, size_t ws_size,
                              hipStream_t stream)
{
    enum { CFG = 0, AST = 1, PT = 2, FT = 3 };
    const int Nnt[4] = {20000, 100000, 50, 10};
    const int dtp[8] = {CFG, AST, CFG, AST, CFG, PT, CFG, FT};

    const float* cfg_label   = (const float*)d_in[0];
    const float* cfg_content = (const float*)d_in[1];
    const float* ast_label   = (const float*)d_in[2];
    const float* ast_content = (const float*)d_in[3];
    const int* esrc[8]; const int* edst[8]; int E[8];
    for (int i = 0; i < 8; ++i) {
        esrc[i] = (const int*)d_in[4 + 2 * i];
        edst[i] = (const int*)d_in[5 + 2 * i];
        E[i]    = in_sizes[4 + 2 * i];
    }
    const float* W_cfg_lab = (const float*)d_in[20]; const float* b_cfg_lab = (const float*)d_in[21];
    const float* W_cfg_con = (const float*)d_in[22]; const float* b_cfg_con = (const float*)d_in[23];
    const float* W_ast_lab = (const float*)d_in[24]; const float* b_ast_lab = (const float*)d_in[25];
    const float* W_ast_con = (const float*)d_in[26]; const float* b_ast_con = (const float*)d_in[27];
    const float* ptest_emb = (const float*)d_in[28];
    const float* ftest_emb = (const float*)d_in[29];
    const float* Wl[5] = {(const float*)d_in[30], (const float*)d_in[32], (const float*)d_in[34],
                          (const float*)d_in[36], (const float*)d_in[38]};
    const float* bl[5] = {(const float*)d_in[31], (const float*)d_in[33], (const float*)d_in[35],
                          (const float*)d_in[37], (const float*)d_in[39]};
    const float* W_dec = (const float*)d_in[40];
    const float* b_dec = (const float*)d_in[41];

    // -------- workspace carve (~480 MB; ws budget is ~512 MiB — round-5 OOM
    // at 562 MB was the crash; WhA/WhC now ALIAS one buffer, never co-live) ---
    char* ws = (char*)d_ws;
    size_t off = 0;
    auto carve = [&](size_t bytes) -> void* {
        void* p = ws + off;
        off = (off + bytes + 255) & ~(size_t)255;
        return p;
    };
    float* F[4];  float* F2[4];
    F[CFG]  = (float*)carve((size_t)20000  * 512 * 4);
    F[AST]  = (float*)carve((size_t)100000 * 512 * 4);
    F[PT]   = (float*)carve((size_t)50     * 512 * 4);
    F[FT]   = (float*)carve((size_t)10     * 512 * 4);
    F2[CFG] = (float*)carve((size_t)20000  * 256 * 4);
    F2[AST] = (float*)carve((size_t)100000 * 256 * 4);
    F2[PT]  = (float*)carve((size_t)50     * 256 * 4);
    F2[FT]  = (float*)carve((size_t)10     * 256 * 4);
    // shared transform buffer: max(100000*256, 20000*1024) = 25.6M floats
    float* WhS = (float*)carve((size_t)100000 * 256 * 4);
    float* WhA = WhS;        // ast transforms   [100000, dout]
    float* WhC = WhS;        // fused cfg transforms [20000, 4*dout] (after WhA dead)
    float* WhP = (float*)carve((size_t)50  * 256 * 4);
    float* WhF = (float*)carve((size_t)10  * 256 * 4);
    float* P   = (float*)carve((size_t)50  * 256 * 4);      // pt/ft partial staging
    float* Bp  = (float*)carve((size_t)512 * 1024 * 4);     // packed cfg weights
    float* bp  = (float*)carve((size_t)1024 * 4);

    int Nd[8], cntoff[8];
    int totc = 0, tote = 0;
    for (int i = 0; i < 8; ++i) {
        Nd[i] = Nnt[dtp[i]];
        cntoff[i] = totc;
        totc += Nd[i]; tote += E[i];
    }
    int* cnt_all = (int*)carve((size_t)totc * 4);
    int* cur_all = (int*)carve((size_t)totc * 4);
    int* G       = (int*)carve((size_t)(totc + 1) * 4);     // global excl scan
    const int nb = (totc + SCB * SCI - 1) / (SCB * SCI);
    int* bsum    = (int*)carve((size_t)nb * 4);
    int* csr_all = (int*)carve((size_t)tote * 4);

    // -------- CSR build (once per call) --------
    zero_i32_kernel<<<(totc + 255) / 256, 256, 0, stream>>>(cnt_all, totc);
    zero_i32_kernel<<<(totc + 255) / 256, 256, 0, stream>>>(cur_all, totc);
    for (int i = 0; i < 8; ++i)
        count_kernel<<<(E[i] + 255) / 256, 256, 0, stream>>>(edst[i], E[i], cnt_all + cntoff[i]);
    scan_p1_kernel<<<nb, SCB, 0, stream>>>(cnt_all, totc, G, bsum);
    scan_p2_kernel<<<1, 64, 0, stream>>>(bsum, nb);
    scan_p3_kernel<<<(totc + 255) / 256, 256, 0, stream>>>(G, totc, bsum, tote);
    for (int i = 0; i < 8; ++i)
        fill_kernel<<<(E[i] + 255) / 256, 256, 0, stream>>>(
            esrc[i], edst[i], E[i], G + cntoff[i], cur_all + cntoff[i], csr_all);

    // -------- encoders: h0 into F[:,0:128] (stride 512) --------
    {
        dim3 g1((20000 + BM - 1) / BM, 1), g2((100000 + BM - 1) / BM, 1);
        gemm_bias_kernel<<<g1, 256, 0, stream>>>(cfg_label, 80, W_cfg_lab, b_cfg_lab,
                                                 F[CFG], 512, 0, 20000, 80, 64);
        gemm_bias_kernel<<<g1, 256, 0, stream>>>(cfg_content, 300, W_cfg_con, b_cfg_con,
                                                 F[CFG], 512, 64, 20000, 300, 64);
        gemm_bias_kernel<<<g2, 256, 0, stream>>>(ast_label, 80, W_ast_lab, b_ast_lab,
                                                 F[AST], 512, 0, 100000, 80, 64);
        gemm_bias_kernel<<<g2, 256, 0, stream>>>(ast_content, 300, W_ast_con, b_ast_con,
                                                 F[AST], 512, 64, 100000, 300, 64);
    }
    bcast_kernel<<<(50 * 128 + 255) / 256, 256, 0, stream>>>(ptest_emb, F[PT], 512, 50);
    bcast_kernel<<<(10 * 128 + 255) / 256, 256, 0, stream>>>(ftest_emb, F[FT], 512, 10);

    // -------- aggregation helpers --------
    auto agg = [&](int i, int dout, const float* Whp, int ldWh, int colWh,
                   float* outp, int ldo, int col0, bool acc) {
        const int* roff = G + cntoff[i];
        const int Ndst  = Nd[i];
        if (dout == 128) {
            int grid = (Ndst + 7) / 8;
            if (acc) agg_wave_kernel<128, true ><<<grid, 256, 0, stream>>>(Whp, ldWh, colWh, roff, csr_all, outp, ldo, col0, Ndst);
            else     agg_wave_kernel<128, false><<<grid, 256, 0, stream>>>(Whp, ldWh, colWh, roff, csr_all, outp, ldo, col0, Ndst);
        } else {
            int grid = (Ndst + 3) / 4;
            if (acc) agg_wave_kernel<256, true ><<<grid, 256, 0, stream>>>(Whp, ldWh, colWh, roff, csr_all, outp, ldo, col0, Ndst);
            else     agg_wave_kernel<256, false><<<grid, 256, 0, stream>>>(Whp, ldWh, colWh, roff, csr_all, outp, ldo, col0, Ndst);
        }
    };
    auto aggP = [&](int i, int dout, const float* Whp, int ldWh, int colWh,
                    float* outp, int ldo, int col0) {
        const int* roff = G + cntoff[i];
        const int Ndst  = Nd[i];
        const int SEGS  = (Ndst <= 10) ? 204 : 40;
        zero_f32_kernel<<<(Ndst * dout + 255) / 256, 256, 0, stream>>>(P, Ndst * dout);
        if (dout == 128)
            agg_part_kernel<128><<<Ndst * SEGS, 256, 0, stream>>>(Whp, ldWh, colWh, roff, csr_all, P, SEGS);
        else
            agg_part_kernel<256><<<Ndst * SEGS, 256, 0, stream>>>(Whp, ldWh, colWh, roff, csr_all, P, SEGS);
        agg_fin_kernel<<<(Ndst * dout + 255) / 256, 256, 0, stream>>>(
            P, roff, outp, ldo, col0, Ndst, dout);
    };

    // -------- one hetero-GCN layer --------
    // etypes: 0 cfg->cfg, 1 ast->ast, 2 ast->cfg, 3 cfg->ast,
    //         4 pt->cfg, 5 cfg->pt, 6 ft->cfg, 7 cfg->ft
    auto run_layer = [&](const float* Wstack, const float* bstack, int din, int dout,
                         float* const* inB, int ldin, float* const* outB, int ldout,
                         int colout) {
        // pack cfg-source weights (etypes 0,3,5,7) into Bp [din, 4*dout]
        const int wtot = din * 4 * dout;
        pack_w_kernel<<<(wtot + 255) / 256, 256, 0, stream>>>(
            Wstack, bstack, din, dout, make_int4(0, 3, 5, 7), Bp, bp);

        // ast-source etype 1 (ast->ast): first writer of ast
        {
            dim3 g((100000 + GM - 1) / GM, dout / GN);
            gemm128_kernel<<<g, 256, 0, stream>>>(
                inB[AST], ldin, Wstack + (size_t)1 * din * dout, bstack + 1 * dout,
                WhA, dout, 0, 100000, din, dout);
            agg(1, dout, WhA, dout, 0, outB[AST], ldout, colout, false);
        }
        // ast-source etype 2 (ast->cfg): first writer of cfg (reuses WhA)
        {
            dim3 g((100000 + GM - 1) / GM, dout / GN);
            gemm128_kernel<<<g, 256, 0, stream>>>(
                inB[AST], ldin, Wstack + (size_t)2 * din * dout, bstack + 2 * dout,
                WhA, dout, 0, 100000, din, dout);
            agg(2, dout, WhA, dout, 0, outB[CFG], ldout, colout, false);
        }
        // fused cfg-source GEMM: WhC [20000, 4*dout], cols [0,3,5,7]*dout
        // (WhC aliases WhA — safe: all WhA readers precede this on the stream)
        {
            dim3 g((20000 + GM - 1) / GM, (4 * dout) / GN);
            gemm128_kernel<<<g, 256, 0, stream>>>(
                inB[CFG], ldin, Bp, bp, WhC, 4 * dout, 0, 20000, din, 4 * dout);
            agg (0, dout, WhC, 4 * dout, 0 * dout, outB[CFG], ldout, colout, true);
            agg (3, dout, WhC, 4 * dout, 1 * dout, outB[AST], ldout, colout, true);
            aggP(5, dout, WhC, 4 * dout, 2 * dout, outB[PT],  ldout, colout);
            aggP(7, dout, WhC, 4 * dout, 3 * dout, outB[FT],  ldout, colout);
        }
        // pt-source etype 4 (pt->cfg)
        {
            dim3 g(1, dout / BN);
            gemm_bias_kernel<<<g, 256, 0, stream>>>(
                inB[PT], ldin, Wstack + (size_t)4 * din * dout, bstack + 4 * dout,
                WhP, dout, 0, 50, din, dout);
            agg(4, dout, WhP, dout, 0, outB[CFG], ldout, colout, true);
        }
        // ft-source etype 6 (ft->cfg)
        {
            dim3 g(1, dout / BN);
            gemm_bias_kernel<<<g, 256, 0, stream>>>(
                inB[FT], ldin, Wstack + (size_t)6 * din * dout, bstack + 6 * dout,
                WhF, dout, 0, 10, din, dout);
            agg(6, dout, WhF, dout, 0, outB[CFG], ldout, colout, true);
        }
    };

    // L1: F[:,0:128] -> F2[:,0:128]
    run_layer(Wl[0], bl[0], 128, 128, F,  512, F2, 256, 0);
    // L2: F2[:,0:128] -> F2[:,128:256]  (concat -> F2[:,0:256])
    run_layer(Wl[1], bl[1], 128, 128, F2, 256, F2, 256, 128);
    // L3: F2[:,0:256] -> F[:,0:256]
    run_layer(Wl[2], bl[2], 256, 256, F2, 256, F,  512, 0);
    // L4: F[:,0:256] -> F[:,256:512]   (concat -> F[:,0:512])
    run_layer(Wl[3], bl[3], 256, 256, F,  512, F,  512, 256);
    // L5: F[:,0:512] -> F2[:,0:128]
    run_layer(Wl[4], bl[4], 512, 128, F,  512, F2, 256, 0);

    // -------- decoder + softmax --------
    float* out = (float*)d_out;
    decoder_kernel<<<(20000 + 255) / 256, 256, 0, stream>>>(
        F2[CFG], 256, 20000, W_dec, b_dec, out + 0, out + 40000);
    decoder_kernel<<<(100000 + 255) / 256, 256, 0, stream>>>(
        F2[AST], 256, 100000, W_dec, b_dec, out + 80000, out + 280000);
}

// Round 10
// 4001.732 us; speedup vs baseline: 1.2183x; 1.2183x over previous
//
#include <hip/hip_runtime.h>

// ============================ 64-wide GEMM (encoders, tiny) ==================
#define BM 64
#define BN 64
#define BK 16

__global__ __launch_bounds__(256) void gemm_bias_kernel(
    const float* __restrict__ A, int lda,
    const float* __restrict__ W,        // [K, DOUT] row-major
    const float* __restrict__ bias,     // [DOUT]
    float* __restrict__ C, int ldc, int col0,
    int N, int K, int DOUT)
{
    __shared__ float As[BK][BM + 4];
    __shared__ float Bs[BK][BN + 4];
    const int tid = threadIdx.x;
    const int tx = tid & 15, ty = tid >> 4;
    const int m0 = blockIdx.x * BM, n0 = blockIdx.y * BN;
    float acc[4][4] = {};
    const int ar = tid >> 2, ak = (tid & 3) << 2;
    const int br = tid >> 4, bn = (tid & 15) << 2;

    for (int k0 = 0; k0 < K; k0 += BK) {
        float4 av = make_float4(0.f, 0.f, 0.f, 0.f);
        int grow = m0 + ar, gk = k0 + ak;
        if (grow < N) {
            if (gk + 3 < K) {
                av = *(const float4*)(A + (long long)grow * lda + gk);
            } else {
                float t0 = 0.f, t1 = 0.f, t2 = 0.f, t3 = 0.f;
                if (gk + 0 < K) t0 = A[(long long)grow * lda + gk + 0];
                if (gk + 1 < K) t1 = A[(long long)grow * lda + gk + 1];
                if (gk + 2 < K) t2 = A[(long long)grow * lda + gk + 2];
                if (gk + 3 < K) t3 = A[(long long)grow * lda + gk + 3];
                av = make_float4(t0, t1, t2, t3);
            }
        }
        As[ak + 0][ar] = av.x; As[ak + 1][ar] = av.y;
        As[ak + 2][ar] = av.z; As[ak + 3][ar] = av.w;

        float4 bv = make_float4(0.f, 0.f, 0.f, 0.f);
        int gbk = k0 + br, gn = n0 + bn;
        if (gbk < K && gn + 3 < DOUT)
            bv = *(const float4*)(W + (long long)gbk * DOUT + gn);
        *(float4*)&Bs[br][bn] = bv;
        __syncthreads();

        #pragma unroll
        for (int kk = 0; kk < BK; ++kk) {
            float4 a4 = *(const float4*)&As[kk][ty << 2];
            float4 b4 = *(const float4*)&Bs[kk][tx << 2];
            float a[4] = {a4.x, a4.y, a4.z, a4.w};
            float b[4] = {b4.x, b4.y, b4.z, b4.w};
            #pragma unroll
            for (int i = 0; i < 4; ++i)
                #pragma unroll
                for (int j = 0; j < 4; ++j)
                    acc[i][j] = fmaf(a[i], b[j], acc[i][j]);
        }
        __syncthreads();
    }

    #pragma unroll
    for (int i = 0; i < 4; ++i) {
        int gm = m0 + (ty << 2) + i;
        if (gm >= N) continue;
        #pragma unroll
        for (int j = 0; j < 4; ++j) {
            int gn = n0 + (tx << 2) + j;
            if (gn < DOUT)
                C[(long long)gm * ldc + col0 + gn] = acc[i][j] + bias[gn];
        }
    }
}

// ======== 128x128 GEMM, single-buffered (round-4 proven: 197us, VGPR 64) =====
// requires: K % 16 == 0, DOUT % 128 == 0
#define GM 128
#define GN 128
#define GK 16

__global__ __launch_bounds__(256) void gemm128_kernel(
    const float* __restrict__ A, int lda,
    const float* __restrict__ W,
    const float* __restrict__ bias,
    float* __restrict__ C, int ldc, int col0,
    int N, int K, int DOUT)
{
    __shared__ float As[GK][GM + 4];
    __shared__ float Bs[GK][GN + 4];
    const int tid = threadIdx.x;
    const int tx = tid & 15, ty = tid >> 4;
    const int m0 = blockIdx.x * GM, n0 = blockIdx.y * GN;
    float acc[8][8] = {};

    const int ar = tid >> 1, ak = (tid & 1) << 3;   // 128 rows x (2 x 8k)
    const int br = tid >> 4, bn = (tid & 15) << 3;  // 16 k x (16 x 8 cols)

    for (int k0 = 0; k0 < K; k0 += GK) {
        int grow = m0 + ar, gk = k0 + ak;
        float4 a0 = make_float4(0.f, 0.f, 0.f, 0.f), a1 = a0;
        if (grow < N) {
            a0 = *(const float4*)(A + (long long)grow * lda + gk);
            a1 = *(const float4*)(A + (long long)grow * lda + gk + 4);
        }
        As[ak + 0][ar] = a0.x; As[ak + 1][ar] = a0.y;
        As[ak + 2][ar] = a0.z; As[ak + 3][ar] = a0.w;
        As[ak + 4][ar] = a1.x; As[ak + 5][ar] = a1.y;
        As[ak + 6][ar] = a1.z; As[ak + 7][ar] = a1.w;

        int gbk = k0 + br, gn = n0 + bn;
        float4 b0 = *(const float4*)(W + (long long)gbk * DOUT + gn);
        float4 b1 = *(const float4*)(W + (long long)gbk * DOUT + gn + 4);
        *(float4*)&Bs[br][bn] = b0;
        *(float4*)&Bs[br][bn + 4] = b1;
        __syncthreads();

        #pragma unroll
        for (int kk = 0; kk < GK; ++kk) {
            float4 aa0 = *(const float4*)&As[kk][ty << 2];
            float4 aa1 = *(const float4*)&As[kk][64 + (ty << 2)];
            float4 bb0 = *(const float4*)&Bs[kk][tx << 2];
            float4 bb1 = *(const float4*)&Bs[kk][64 + (tx << 2)];
            float a[8] = {aa0.x, aa0.y, aa0.z, aa0.w, aa1.x, aa1.y, aa1.z, aa1.w};
            float b[8] = {bb0.x, bb0.y, bb0.z, bb0.w, bb1.x, bb1.y, bb1.z, bb1.w};
            #pragma unroll
            for (int i = 0; i < 8; ++i)
                #pragma unroll
                for (int j = 0; j < 8; ++j)
                    acc[i][j] = fmaf(a[i], b[j], acc[i][j]);
        }
        __syncthreads();
    }

    #pragma unroll
    for (int half = 0; half < 2; ++half) {
        #pragma unroll
        for (int i = 0; i < 4; ++i) {
            int gm = m0 + half * 64 + (ty << 2) + i;
            if (gm >= N) continue;
            int ai = half * 4 + i;
            #pragma unroll
            for (int jh = 0; jh < 2; ++jh) {
                int gn = n0 + jh * 64 + (tx << 2);
                float4 r;
                r.x = acc[ai][jh * 4 + 0] + bias[gn + 0];
                r.y = acc[ai][jh * 4 + 1] + bias[gn + 1];
                r.z = acc[ai][jh * 4 + 2] + bias[gn + 2];
                r.w = acc[ai][jh * 4 + 3] + bias[gn + 3];
                *(float4*)(C + (long long)gm * ldc + col0 + gn) = r;
            }
        }
    }
}

// ================= weight pack: Bp[k][et*dout+c] = W[etl[et]][k][c] ==========
__global__ void pack_w_kernel(const float* __restrict__ Wstack,
                              const float* __restrict__ bstack,
                              int din, int dout, int4 etl,
                              float* __restrict__ Bp, float* __restrict__ bp)
{
    const int idx = blockIdx.x * blockDim.x + threadIdx.x;
    const int wtot = din * 4 * dout;
    if (idx < wtot) {
        const int col = idx % (4 * dout), k = idx / (4 * dout);
        const int et = col / dout, c = col % dout;
        const int e = (&etl.x)[et];
        Bp[idx] = Wstack[((size_t)e * din + k) * dout + c];
    }
    if (idx < 4 * dout) {
        const int et = idx / dout, c = idx % dout;
        const int e = (&etl.x)[et];
        bp[idx] = bstack[e * dout + c];
    }
}

// ====================== CSR-gather aggregation kernels =======================
// out[node] (=|+=) (1/deg) * sum_{e in CSR[node]} Wh[csr[e]][colWh..]
template<int DOUT, bool ACC>
__global__ __launch_bounds__(256) void agg_wave_kernel(
    const float* __restrict__ Wh, int ldWh, int colWh,
    const int* __restrict__ roff, const int* __restrict__ csr,
    float* __restrict__ out, int ldo, int col0, int N)
{
    constexpr int CT = DOUT / 4;
    constexpr int NPB = 256 / CT;
    const int node = blockIdx.x * NPB + threadIdx.x / CT;
    if (node >= N) return;
    const int c = threadIdx.x % CT;
    const int beg = roff[node], end = roff[node + 1];
    float sx = 0.f, sy = 0.f, sz = 0.f, sw = 0.f;
    for (int e = beg; e < end; ++e) {
        const int s = csr[e];
        const float4 v = *(const float4*)(Wh + (long long)s * ldWh + colWh + (c << 2));
        sx += v.x; sy += v.y; sz += v.z; sw += v.w;
    }
    const int deg = end - beg;
    const float sc = deg > 0 ? 1.0f / (float)deg : 0.0f;
    float* po = out + (long long)node * ldo + col0 + (c << 2);
    float4 r; r.x = sx * sc; r.y = sy * sc; r.z = sz * sc; r.w = sw * sc;
    if (ACC) {
        const float4 o = *(const float4*)po;
        r.x += o.x; r.y += o.y; r.z += o.z; r.w += o.w;
    }
    *(float4*)po = r;
}

// ---- multi-block partial aggregation for tiny-N / huge-degree dsts (pt/ft) --
template<int DOUT>
__global__ __launch_bounds__(256) void agg_part_kernel(
    const float* __restrict__ Wh, int ldWh, int colWh,
    const int* __restrict__ roff, const int* __restrict__ csr,
    float* __restrict__ P, int SEGS)
{
    constexpr int CT = DOUT / 4;
    constexpr int EP = 256 / CT;
    const int node = blockIdx.x / SEGS;
    const int seg  = blockIdx.x % SEGS;
    const int c = threadIdx.x % CT;
    const int g = threadIdx.x / CT;
    const int beg = roff[node], end = roff[node + 1];
    float sx = 0.f, sy = 0.f, sz = 0.f, sw = 0.f;
    for (int e = beg + seg * EP + g; e < end; e += SEGS * EP) {
        const int s = csr[e];
        const float4 v = *(const float4*)(Wh + (long long)s * ldWh + colWh + (c << 2));
        sx += v.x; sy += v.y; sz += v.z; sw += v.w;
    }
    __shared__ float4 red[256];
    red[threadIdx.x] = make_float4(sx, sy, sz, sw);
    __syncthreads();
    if (g == 0) {
        #pragma unroll
        for (int k = 1; k < EP; ++k) {
            const float4 v = red[k * CT + c];
            sx += v.x; sy += v.y; sz += v.z; sw += v.w;
        }
        float* pp = P + (long long)node * DOUT + (c << 2);
        atomicAdd(pp + 0, sx);
        atomicAdd(pp + 1, sy);
        atomicAdd(pp + 2, sz);
        atomicAdd(pp + 3, sw);
    }
}

__global__ void agg_fin_kernel(const float* __restrict__ P,
                               const int* __restrict__ roff,
                               float* __restrict__ out, int ldo, int col0,
                               int N, int DOUT)
{
    int idx = blockIdx.x * blockDim.x + threadIdx.x;
    if (idx >= N * DOUT) return;
    int n = idx / DOUT, c = idx % DOUT;
    int deg = roff[n + 1] - roff[n];
    float sc = deg > 0 ? 1.0f / (float)deg : 0.0f;
    out[(long long)n * ldo + col0 + c] = P[idx] * sc;
}

__global__ void zero_f32_kernel(float* __restrict__ p, int n)
{
    int i = blockIdx.x * blockDim.x + threadIdx.x;
    if (i < n) p[i] = 0.f;
}

// ============================ CSR build helpers ==============================
__global__ void zero_i32_kernel(int* __restrict__ p, int n)
{
    int i = blockIdx.x * blockDim.x + threadIdx.x;
    if (i < n) p[i] = 0;
}

__global__ void count_kernel(const int* __restrict__ dst, int E, int* __restrict__ cnt)
{
    int i = blockIdx.x * blockDim.x + threadIdx.x;
    if (i < E) atomicAdd(&cnt[dst[i]], 1);
}

// 3-phase global exclusive scan over cnt[0..n) -> G[0..n], G[n]=tote
#define SCB 256
#define SCI 4
__global__ __launch_bounds__(SCB) void scan_p1_kernel(
    const int* __restrict__ cnt, int n, int* __restrict__ G, int* __restrict__ bsum)
{
    __shared__ int sh[SCB];
    const int base = blockIdx.x * (SCB * SCI);
    const int tb = base + threadIdx.x * SCI;
    int v[SCI]; int tsum = 0;
    #pragma unroll
    for (int j = 0; j < SCI; ++j) {
        int idx = tb + j;
        v[j] = (idx < n) ? cnt[idx] : 0;
        tsum += v[j];
    }
    sh[threadIdx.x] = tsum;
    __syncthreads();
    int incl = tsum;
    for (int ofs = 1; ofs < SCB; ofs <<= 1) {
        int t = (threadIdx.x >= (unsigned)ofs) ? sh[threadIdx.x - ofs] : 0;
        __syncthreads();
        incl += t;
        sh[threadIdx.x] = incl;
        __syncthreads();
    }
    if (threadIdx.x == SCB - 1) bsum[blockIdx.x] = incl;
    int run = incl - tsum;                 // exclusive prefix of this thread
    #pragma unroll
    for (int j = 0; j < SCI; ++j) {
        int idx = tb + j;
        if (idx < n) G[idx] = run;
        run += v[j];
    }
}

__global__ void scan_p2_kernel(int* __restrict__ bsum, int nb)
{
    if (blockIdx.x == 0 && threadIdx.x == 0) {
        int run = 0;
        for (int b = 0; b < nb; ++b) { int t = bsum[b]; bsum[b] = run; run += t; }
    }
}

__global__ void scan_p3_kernel(int* __restrict__ G, int n,
                               const int* __restrict__ bsum, int tote)
{
    int i = blockIdx.x * blockDim.x + threadIdx.x;
    if (i < n) G[i] += bsum[i / (SCB * SCI)];
    if (i == 0) G[n] = tote;
}

__global__ void fill_kernel(const int* __restrict__ src, const int* __restrict__ dst,
                            int E, const int* __restrict__ G,   // per-etype base
                            int* __restrict__ cur,              // per-etype base
                            int* __restrict__ csr)              // GLOBAL base
{
    int i = blockIdx.x * blockDim.x + threadIdx.x;
    if (i < E) {
        const int d = dst[i];
        const int pos = atomicAdd(&cur[d], 1);
        csr[G[d] + pos] = src[i];
    }
}

// ============================== misc kernels =================================
__global__ void bcast_kernel(const float* __restrict__ emb, float* __restrict__ Fp,
                             int ld, int N)
{
    int idx = blockIdx.x * blockDim.x + threadIdx.x;
    if (idx >= N * 128) return;
    int r = idx >> 7, c = idx & 127;
    Fp[(long long)r * ld + c] = emb[c];
}

__global__ void decoder_kernel(const float* __restrict__ H, int ld, int N,
                               const float* __restrict__ Wd,
                               const float* __restrict__ bd,
                               float* __restrict__ logits, float* __restrict__ soft)
{
    int n = blockIdx.x * blockDim.x + threadIdx.x;
    if (n >= N) return;
    const float* h = H + (long long)n * ld;
    float s0 = bd[0], s1 = bd[1];
    #pragma unroll
    for (int k = 0; k < 128; k += 4) {
        float4 hv = *(const float4*)(h + k);
        s0 = fmaf(hv.x, Wd[2 * (k + 0) + 0], s0); s1 = fmaf(hv.x, Wd[2 * (k + 0) + 1], s1);
        s0 = fmaf(hv.y, Wd[2 * (k + 1) + 0], s0); s1 = fmaf(hv.y, Wd[2 * (k + 1) + 1], s1);
        s0 = fmaf(hv.z, Wd[2 * (k + 2) + 0], s0); s1 = fmaf(hv.z, Wd[2 * (k + 2) + 1], s1);
        s0 = fmaf(hv.w, Wd[2 * (k + 3) + 0], s0); s1 = fmaf(hv.w, Wd[2 * (k + 3) + 1], s1);
    }
    logits[2 * n + 0] = s0;
    logits[2 * n + 1] = s1;
    float m = fmaxf(s0, s1);
    float e0 = expf(s0 - m), e1 = expf(s1 - m);
    float invs = 1.f / (e0 + e1);
    soft[2 * n + 0] = e0 * invs;
    soft[2 * n + 1] = e1 * invs;
}

// ================================== host =====================================
extern "C" void kernel_launch(void* const* d_in, const int* in_sizes, int n_in,
                              void* d_out, int out_size, void* d_ws, size_t ws_size,
                              hipStream_t stream)
{
    enum { CFG = 0, AST = 1, PT = 2, FT = 3 };
    const int Nnt[4] = {20000, 100000, 50, 10};
    const int dtp[8] = {CFG, AST, CFG, AST, CFG, PT, CFG, FT};

    const float* cfg_label   = (const float*)d_in[0];
    const float* cfg_content = (const float*)d_in[1];
    const float* ast_label   = (const float*)d_in[2];
    const float* ast_content = (const float*)d_in[3];
    const int* esrc[8]; const int* edst[8]; int E[8];
    for (int i = 0; i < 8; ++i) {
        esrc[i] = (const int*)d_in[4 + 2 * i];
        edst[i] = (const int*)d_in[5 + 2 * i];
        E[i]    = in_sizes[4 + 2 * i];
    }
    const float* W_cfg_lab = (const float*)d_in[20]; const float* b_cfg_lab = (const float*)d_in[21];
    const float* W_cfg_con = (const float*)d_in[22]; const float* b_cfg_con = (const float*)d_in[23];
    const float* W_ast_lab = (const float*)d_in[24]; const float* b_ast_lab = (const float*)d_in[25];
    const float* W_ast_con = (const float*)d_in[26]; const float* b_ast_con = (const float*)d_in[27];
    const float* ptest_emb = (const float*)d_in[28];
    const float* ftest_emb = (const float*)d_in[29];
    const float* Wl[5] = {(const float*)d_in[30], (const float*)d_in[32], (const float*)d_in[34],
                          (const float*)d_in[36], (const float*)d_in[38]};
    const float* bl[5] = {(const float*)d_in[31], (const float*)d_in[33], (const float*)d_in[35],
                          (const float*)d_in[37], (const float*)d_in[39]};
    const float* W_dec = (const float*)d_in[40];
    const float* b_dec = (const float*)d_in[41];

    // -------- workspace carve (~480 MB; WhA/WhC alias one buffer) --------
    char* ws = (char*)d_ws;
    size_t off = 0;
    auto carve = [&](size_t bytes) -> void* {
        void* p = ws + off;
        off = (off + bytes + 255) & ~(size_t)255;
        return p;
    };
    float* F[4];  float* F2[4];
    F[CFG]  = (float*)carve((size_t)20000  * 512 * 4);
    F[AST]  = (float*)carve((size_t)100000 * 512 * 4);
    F[PT]   = (float*)carve((size_t)50     * 512 * 4);
    F[FT]   = (float*)carve((size_t)10     * 512 * 4);
    F2[CFG] = (float*)carve((size_t)20000  * 256 * 4);
    F2[AST] = (float*)carve((size_t)100000 * 256 * 4);
    F2[PT]  = (float*)carve((size_t)50     * 256 * 4);
    F2[FT]  = (float*)carve((size_t)10     * 256 * 4);
    // shared transform buffer: max(100000*256, 20000*1024) = 25.6M floats
    float* WhS = (float*)carve((size_t)100000 * 256 * 4);
    float* WhA = WhS;        // ast transforms   [100000, dout]
    float* WhC = WhS;        // fused cfg transforms [20000, 4*dout] (after WhA dead)
    float* WhP = (float*)carve((size_t)50  * 256 * 4);
    float* WhF = (float*)carve((size_t)10  * 256 * 4);
    float* P   = (float*)carve((size_t)50  * 256 * 4);      // pt/ft partial staging
    float* Bp  = (float*)carve((size_t)512 * 1024 * 4);     // packed cfg weights
    float* bp  = (float*)carve((size_t)1024 * 4);

    int Nd[8], cntoff[8];
    int totc = 0, tote = 0;
    for (int i = 0; i < 8; ++i) {
        Nd[i] = Nnt[dtp[i]];
        cntoff[i] = totc;
        totc += Nd[i]; tote += E[i];
    }
    int* cnt_all = (int*)carve((size_t)totc * 4);
    int* cur_all = (int*)carve((size_t)totc * 4);
    int* G       = (int*)carve((size_t)(totc + 1) * 4);     // global excl scan
    const int nb = (totc + SCB * SCI - 1) / (SCB * SCI);
    int* bsum    = (int*)carve((size_t)nb * 4);
    int* csr_all = (int*)carve((size_t)tote * 4);

    // -------- CSR build (once per call) --------
    zero_i32_kernel<<<(totc + 255) / 256, 256, 0, stream>>>(cnt_all, totc);
    zero_i32_kernel<<<(totc + 255) / 256, 256, 0, stream>>>(cur_all, totc);
    for (int i = 0; i < 8; ++i)
        count_kernel<<<(E[i] + 255) / 256, 256, 0, stream>>>(edst[i], E[i], cnt_all + cntoff[i]);
    scan_p1_kernel<<<nb, SCB, 0, stream>>>(cnt_all, totc, G, bsum);
    scan_p2_kernel<<<1, 64, 0, stream>>>(bsum, nb);
    scan_p3_kernel<<<(totc + 255) / 256, 256, 0, stream>>>(G, totc, bsum, tote);
    for (int i = 0; i < 8; ++i)
        fill_kernel<<<(E[i] + 255) / 256, 256, 0, stream>>>(
            esrc[i], edst[i], E[i], G + cntoff[i], cur_all + cntoff[i], csr_all);

    // -------- encoders: h0 into F[:,0:128] (stride 512) --------
    {
        dim3 g1((20000 + BM - 1) / BM, 1), g2((100000 + BM - 1) / BM, 1);
        gemm_bias_kernel<<<g1, 256, 0, stream>>>(cfg_label, 80, W_cfg_lab, b_cfg_lab,
                                                 F[CFG], 512, 0, 20000, 80, 64);
        gemm_bias_kernel<<<g1, 256, 0, stream>>>(cfg_content, 300, W_cfg_con, b_cfg_con,
                                                 F[CFG], 512, 64, 20000, 300, 64);
        gemm_bias_kernel<<<g2, 256, 0, stream>>>(ast_label, 80, W_ast_lab, b_ast_lab,
                                                 F[AST], 512, 0, 100000, 80, 64);
        gemm_bias_kernel<<<g2, 256, 0, stream>>>(ast_content, 300, W_ast_con, b_ast_con,
                                                 F[AST], 512, 64, 100000, 300, 64);
    }
    bcast_kernel<<<(50 * 128 + 255) / 256, 256, 0, stream>>>(ptest_emb, F[PT], 512, 50);
    bcast_kernel<<<(10 * 128 + 255) / 256, 256, 0, stream>>>(ftest_emb, F[FT], 512, 10);

    // -------- aggregation helpers --------
    auto agg = [&](int i, int dout, const float* Whp, int ldWh, int colWh,
                   float* outp, int ldo, int col0, bool acc) {
        const int* roff = G + cntoff[i];
        const int Ndst  = Nd[i];
        if (dout == 128) {
            int grid = (Ndst + 7) / 8;
            if (acc) agg_wave_kernel<128, true ><<<grid, 256, 0, stream>>>(Whp, ldWh, colWh, roff, csr_all, outp, ldo, col0, Ndst);
            else     agg_wave_kernel<128, false><<<grid, 256, 0, stream>>>(Whp, ldWh, colWh, roff, csr_all, outp, ldo, col0, Ndst);
        } else {
            int grid = (Ndst + 3) / 4;
            if (acc) agg_wave_kernel<256, true ><<<grid, 256, 0, stream>>>(Whp, ldWh, colWh, roff, csr_all, outp, ldo, col0, Ndst);
            else     agg_wave_kernel<256, false><<<grid, 256, 0, stream>>>(Whp, ldWh, colWh, roff, csr_all, outp, ldo, col0, Ndst);
        }
    };
    auto aggP = [&](int i, int dout, const float* Whp, int ldWh, int colWh,
                    float* outp, int ldo, int col0) {
        const int* roff = G + cntoff[i];
        const int Ndst  = Nd[i];
        const int SEGS  = (Ndst <= 10) ? 204 : 40;
        zero_f32_kernel<<<(Ndst * dout + 255) / 256, 256, 0, stream>>>(P, Ndst * dout);
        if (dout == 128)
            agg_part_kernel<128><<<Ndst * SEGS, 256, 0, stream>>>(Whp, ldWh, colWh, roff, csr_all, P, SEGS);
        else
            agg_part_kernel<256><<<Ndst * SEGS, 256, 0, stream>>>(Whp, ldWh, colWh, roff, csr_all, P, SEGS);
        agg_fin_kernel<<<(Ndst * dout + 255) / 256, 256, 0, stream>>>(
            P, roff, outp, ldo, col0, Ndst, dout);
    };

    // -------- one hetero-GCN layer --------
    // etypes: 0 cfg->cfg, 1 ast->ast, 2 ast->cfg, 3 cfg->ast,
    //         4 pt->cfg, 5 cfg->pt, 6 ft->cfg, 7 cfg->ft
    auto run_layer = [&](const float* Wstack, const float* bstack, int din, int dout,
                         float* const* inB, int ldin, float* const* outB, int ldout,
                         int colout) {
        // pack cfg-source weights (etypes 0,3,5,7) into Bp [din, 4*dout]
        const int wtot = din * 4 * dout;
        pack_w_kernel<<<(wtot + 255) / 256, 256, 0, stream>>>(
            Wstack, bstack, din, dout, make_int4(0, 3, 5, 7), Bp, bp);

        // ast-source etype 1 (ast->ast): first writer of ast
        {
            dim3 g((100000 + GM - 1) / GM, dout / GN);
            gemm128_kernel<<<g, 256, 0, stream>>>(
                inB[AST], ldin, Wstack + (size_t)1 * din * dout, bstack + 1 * dout,
                WhA, dout, 0, 100000, din, dout);
            agg(1, dout, WhA, dout, 0, outB[AST], ldout, colout, false);
        }
        // ast-source etype 2 (ast->cfg): first writer of cfg (reuses WhA)
        {
            dim3 g((100000 + GM - 1) / GM, dout / GN);
            gemm128_kernel<<<g, 256, 0, stream>>>(
                inB[AST], ldin, Wstack + (size_t)2 * din * dout, bstack + 2 * dout,
                WhA, dout, 0, 100000, din, dout);
            agg(2, dout, WhA, dout, 0, outB[CFG], ldout, colout, false);
        }
        // fused cfg-source GEMM: WhC [20000, 4*dout], cols [0,3,5,7]*dout
        // (WhC aliases WhA — safe: all WhA readers precede this on the stream)
        {
            dim3 g((20000 + GM - 1) / GM, (4 * dout) / GN);
            gemm128_kernel<<<g, 256, 0, stream>>>(
                inB[CFG], ldin, Bp, bp, WhC, 4 * dout, 0, 20000, din, 4 * dout);
            agg (0, dout, WhC, 4 * dout, 0 * dout, outB[CFG], ldout, colout, true);
            agg (3, dout, WhC, 4 * dout, 1 * dout, outB[AST], ldout, colout, true);
            aggP(5, dout, WhC, 4 * dout, 2 * dout, outB[PT],  ldout, colout);
            aggP(7, dout, WhC, 4 * dout, 3 * dout, outB[FT],  ldout, colout);
        }
        // pt-source etype 4 (pt->cfg)
        {
            dim3 g(1, dout / BN);
            gemm_bias_kernel<<<g, 256, 0, stream>>>(
                inB[PT], ldin, Wstack + (size_t)4 * din * dout, bstack + 4 * dout,
                WhP, dout, 0, 50, din, dout);
            agg(4, dout, WhP, dout, 0, outB[CFG], ldout, colout, true);
        }
        // ft-source etype 6 (ft->cfg)
        {
            dim3 g(1, dout / BN);
            gemm_bias_kernel<<<g, 256, 0, stream>>>(
                inB[FT], ldin, Wstack + (size_t)6 * din * dout, bstack + 6 * dout,
                WhF, dout, 0, 10, din, dout);
            agg(6, dout, WhF, dout, 0, outB[CFG], ldout, colout, true);
        }
    };

    // L1: F[:,0:128] -> F2[:,0:128]
    run_layer(Wl[0], bl[0], 128, 128, F,  512, F2, 256, 0);
    // L2: F2[:,0:128] -> F2[:,128:256]  (concat -> F2[:,0:256])
    run_layer(Wl[1], bl[1], 128, 128, F2, 256, F2, 256, 128);
    // L3: F2[:,0:256] -> F[:,0:256]
    run_layer(Wl[2], bl[2], 256, 256, F2, 256, F,  512, 0);
    // L4: F[:,0:256] -> F[:,256:512]   (concat -> F[:,0:512])
    run_layer(Wl[3], bl[3], 256, 256, F,  512, F,  512, 256);
    // L5: F[:,0:512] -> F2[:,0:128]
    run_layer(Wl[4], bl[4], 512, 128, F,  512, F2, 256, 0);

    // -------- decoder + softmax --------
    float* out = (float*)d_out;
    decoder_kernel<<<(20000 + 255) / 256, 256, 0, stream>>>(
        F2[CFG], 256, 20000, W_dec, b_dec, out + 0, out + 40000);
    decoder_kernel<<<(100000 + 255) / 256, 256, 0, stream>>>(
        F2[AST], 256, 100000, W_dec, b_dec, out + 80000, out + 280000);
}